// Round 2
// baseline (500.432 us; speedup 1.0000x reference)
//
#include <hip/hip_runtime.h>
#include <hip/hip_bf16.h>
#include <stdint.h>

#define B 32
#define S 8192
#define D 256
#define H 256

typedef __attribute__((ext_vector_type(8))) short bf16x8;
typedef __attribute__((ext_vector_type(4))) float f32x4;

__device__ inline unsigned short f2bf(float f) {
  unsigned u = __float_as_uint(f);
  unsigned r = (u + 0x7FFFu + ((u >> 16) & 1u)) >> 16;
  return (unsigned short)r;
}

__device__ inline unsigned pk2bf(float a, float b) {
  // packed fp32x2 -> bf16x2 (RNE); maps to v_cvt_pk_bf16_f32 on gfx950
  __hip_bfloat162 h = __float22bfloat162_rn(make_float2(a, b));
  unsigned u;
  __builtin_memcpy(&u, &h, 4);
  return u;
}

__device__ inline bf16x8 pack8(float4 a, float4 b) {
  union { unsigned u[4]; bf16x8 v; } c;
  c.u[0] = pk2bf(a.x, a.y);
  c.u[1] = pk2bf(a.z, a.w);
  c.u[2] = pk2bf(b.x, b.y);
  c.u[3] = pk2bf(b.z, b.w);
  return c.v;
}

__device__ inline float fast_tanh(float x) {
  float e = __expf(2.0f * x);
  return 1.0f - 2.0f * __builtin_amdgcn_rcpf(1.0f + e);
}

// ---------------------------------------------------------------------------
// Prep: blocks 0..63 swizzle W_e into MFMA-B fragment-sequential bf16;
//       blocks 64..95 run the LSTM cell + dec_proj (one block per batch).
// ---------------------------------------------------------------------------
__global__ __launch_bounds__(1024) void prep_kernel(
    const float* __restrict__ h0, const float* __restrict__ c0,
    const float* __restrict__ start_token, const float* __restrict__ W_k,
    const float* __restrict__ W_r, const float* __restrict__ b_lstm,
    const float* __restrict__ W_e, const float* __restrict__ W_d,
    const float* __restrict__ b_d,
    unsigned short* __restrict__ Wfrag, float* __restrict__ dec) {
  int blk = blockIdx.x;
  int tid = threadIdx.x;

  __shared__ float xs[D], hs[H], zs[4 * H], hv[H], dpp[4][H];

  if (blk < 64) {
    // idx = (((nt*8 + kt)*64 + lane)*8 + j); lane holds B[k][n],
    // n = nt*16 + (lane&15), k = kt*32 + (lane>>4)*8 + j
    int gid = blk * 1024 + tid;
    int j = gid & 7;
    int lane = (gid >> 3) & 63;
    int kt = (gid >> 9) & 7;
    int nt = gid >> 12;
    int n = nt * 16 + (lane & 15);
    int k = kt * 32 + (lane >> 4) * 8 + j;
    Wfrag[gid] = f2bf(W_e[k * H + n]);
  } else {
    int b = blk - 64;
    if (tid < D) xs[tid] = start_token[b * D + tid];
    else if (tid < 2 * D) hs[tid - D] = h0[b * H + (tid - D)];
    __syncthreads();
    {
      int jj = tid;
      float a0 = 0.f, a1 = 0.f, a2 = 0.f, a3 = 0.f;
      #pragma unroll 8
      for (int d = 0; d < D; d += 4) {
        a0 += xs[d + 0] * W_k[(d + 0) * 1024 + jj];
        a1 += xs[d + 1] * W_k[(d + 1) * 1024 + jj];
        a2 += xs[d + 2] * W_k[(d + 2) * 1024 + jj];
        a3 += xs[d + 3] * W_k[(d + 3) * 1024 + jj];
      }
      #pragma unroll 8
      for (int h = 0; h < H; h += 4) {
        a0 += hs[h + 0] * W_r[(h + 0) * 1024 + jj];
        a1 += hs[h + 1] * W_r[(h + 1) * 1024 + jj];
        a2 += hs[h + 2] * W_r[(h + 2) * 1024 + jj];
        a3 += hs[h + 3] * W_r[(h + 3) * 1024 + jj];
      }
      zs[jj] = b_lstm[jj] + ((a0 + a1) + (a2 + a3));
    }
    __syncthreads();
    if (tid < H) {
      float zi = zs[tid], zf = zs[H + tid], zg = zs[2 * H + tid], zo = zs[3 * H + tid];
      float si = 1.0f / (1.0f + expf(-zi));
      float sf = 1.0f / (1.0f + expf(-zf));
      float so = 1.0f / (1.0f + expf(-zo));
      float c = sf * c0[b * H + tid] + si * tanhf(zg);
      hv[tid] = so * tanhf(c);
    }
    __syncthreads();
    {
      int hcol = tid & (H - 1);
      int q = tid >> 8;
      float a = 0.f;
      #pragma unroll 8
      for (int k = q * 64; k < q * 64 + 64; ++k) a += hv[k] * W_d[k * H + hcol];
      dpp[q][hcol] = a;
    }
    __syncthreads();
    if (tid < H)
      dec[b * H + tid] = dpp[0][tid] + dpp[1][tid] + dpp[2][tid] + dpp[3][tid] + b_d[tid];
  }
}

// ---------------------------------------------------------------------------
// Main: one block = 64 encoder rows, full N=256. Waves split 2x2 over MxN:
// wave (wr,wc) does rows wr*32..+32, cols wc*128..+128. A-fragments load
// DIRECTLY from global (no LDS staging, no K-loop barriers); bf16 convert
// in registers. Fused tanh * v_w epilogue, shuffle-reduce, scores out.
// ---------------------------------------------------------------------------
__global__ __launch_bounds__(256, 2) void attn_kernel(
    const float* __restrict__ enc, const unsigned short* __restrict__ Wfrag,
    const float* __restrict__ dec, const float* __restrict__ b_e,
    const float* __restrict__ v_w, float* __restrict__ scores) {
  __shared__ float part_sh[2][64];

  int tid = threadIdx.x;
  int b = blockIdx.x >> 7;
  int st = blockIdx.x & 127;
  long row0 = (long)b * S + st * 64;

  int wave = tid >> 6, lane = tid & 63;
  int ml = lane & 15, kg = lane >> 4;
  int wr = wave >> 1, wc = wave & 1;

  // Per-lane A row base pointers (i = 0,1 -> rows wr*32 + i*16 + ml)
  const float* arow0 = enc + (row0 + wr * 32 + ml) * (long)D + kg * 8;
  const float* arow1 = arow0 + 16 * D;

  // Epilogue constants (issued early; L2-hot, consumed after K-loop)
  float bs[8], vw8[8];
  #pragma unroll
  for (int q = 0; q < 8; ++q) {
    int n = wc * 128 + q * 16 + ml;
    bs[q] = b_e[n] + dec[b * H + n];
    vw8[q] = v_w[n];
  }

  f32x4 acc[2][8];
  #pragma unroll
  for (int i = 0; i < 2; ++i)
    #pragma unroll
    for (int q = 0; q < 8; ++q) acc[i][q] = (f32x4){0.f, 0.f, 0.f, 0.f};

  #pragma unroll
  for (int kt = 0; kt < 8; ++kt) {
    // B fragments: nt = wc*8 + q, fragment-sequential (1KB/instr, L2-hot)
    bf16x8 wfr[8];
    #pragma unroll
    for (int q = 0; q < 8; ++q) {
      const unsigned short* p = Wfrag + ((size_t)(((wc * 8 + q) * 8 + kt) * 64 + lane) << 3);
      wfr[q] = *(const bf16x8*)p;
    }
    // A fragments direct from global: lane (ml,kg) reads 8 consecutive fp32
    float4 a0lo = *(const float4*)(arow0 + kt * 32);
    float4 a0hi = *(const float4*)(arow0 + kt * 32 + 4);
    float4 a1lo = *(const float4*)(arow1 + kt * 32);
    float4 a1hi = *(const float4*)(arow1 + kt * 32 + 4);
    bf16x8 afr0 = pack8(a0lo, a0hi);
    bf16x8 afr1 = pack8(a1lo, a1hi);
    #pragma unroll
    for (int q = 0; q < 8; ++q) {
      acc[0][q] = __builtin_amdgcn_mfma_f32_16x16x32_bf16(afr0, wfr[q], acc[0][q], 0, 0, 0);
      acc[1][q] = __builtin_amdgcn_mfma_f32_16x16x32_bf16(afr1, wfr[q], acc[1][q], 0, 0, 0);
    }
  }

  // Epilogue: t = tanh(acc + bias[n]); partial[m] += t * v_w[n]
  float part[8];
  #pragma unroll
  for (int v = 0; v < 8; ++v) part[v] = 0.f;
  #pragma unroll
  for (int q = 0; q < 8; ++q) {
    #pragma unroll
    for (int i = 0; i < 2; ++i)
      #pragma unroll
      for (int r = 0; r < 4; ++r)
        part[i * 4 + r] += fast_tanh(acc[i][q][r] + bs[q]) * vw8[q];
  }
  // reduce over the 16 column-lanes (lane&15)
  #pragma unroll
  for (int m = 1; m < 16; m <<= 1)
    #pragma unroll
    for (int v = 0; v < 8; ++v) part[v] += __shfl_xor(part[v], m, 64);
  if (ml == 0) {
    #pragma unroll
    for (int i = 0; i < 2; ++i)
      #pragma unroll
      for (int r = 0; r < 4; ++r)
        part_sh[wc][wr * 32 + i * 16 + kg * 4 + r] = part[i * 4 + r];
  }
  __syncthreads();
  if (tid < 64)
    scores[row0 + tid] = part_sh[0][tid] + part_sh[1][tid];  // v_b cancels in softmax
}

// ---------------------------------------------------------------------------
// Softmax over each row of (B, S)
// ---------------------------------------------------------------------------
__global__ __launch_bounds__(1024) void softmax_kernel(
    const float* __restrict__ scores, float* __restrict__ out) {
  int b = blockIdx.x;
  int tid = threadIdx.x;
  __shared__ float red[16];
  const float* src = scores + (long)b * S;
  float v[8];
  float lmax = -1e30f;
  #pragma unroll
  for (int j = 0; j < 8; ++j) {
    v[j] = src[tid + j * 1024];
    lmax = fmaxf(lmax, v[j]);
  }
  #pragma unroll
  for (int m = 1; m < 64; m <<= 1) lmax = fmaxf(lmax, __shfl_xor(lmax, m, 64));
  if ((tid & 63) == 0) red[tid >> 6] = lmax;
  __syncthreads();
  float M = red[0];
  #pragma unroll
  for (int i = 1; i < 16; ++i) M = fmaxf(M, red[i]);
  __syncthreads();
  float ls = 0.f;
  #pragma unroll
  for (int j = 0; j < 8; ++j) {
    v[j] = __expf(v[j] - M);
    ls += v[j];
  }
  #pragma unroll
  for (int m = 1; m < 64; m <<= 1) ls += __shfl_xor(ls, m, 64);
  if ((tid & 63) == 0) red[tid >> 6] = ls;
  __syncthreads();
  float total = 0.f;
  #pragma unroll
  for (int i = 0; i < 16; ++i) total += red[i];
  float inv = __builtin_amdgcn_rcpf(total);
  #pragma unroll
  for (int j = 0; j < 8; ++j) out[(long)b * S + tid + j * 1024] = v[j] * inv;
}

extern "C" void kernel_launch(void* const* d_in, const int* in_sizes, int n_in,
                              void* d_out, int out_size, void* d_ws, size_t ws_size,
                              hipStream_t stream) {
  const float* enc         = (const float*)d_in[0];
  const float* h0          = (const float*)d_in[1];
  const float* c0          = (const float*)d_in[2];
  const float* start_token = (const float*)d_in[3];
  const float* W_k         = (const float*)d_in[4];
  const float* W_r         = (const float*)d_in[5];
  const float* b_lstm      = (const float*)d_in[6];
  const float* W_e         = (const float*)d_in[7];
  const float* b_e         = (const float*)d_in[8];
  const float* W_d         = (const float*)d_in[9];
  const float* b_d         = (const float*)d_in[10];
  const float* v_w         = (const float*)d_in[11];
  // d_in[12] = v_b: softmax(s + c) == softmax(s), cancels exactly.
  float* out = (float*)d_out;

  char* wsb = (char*)d_ws;
  float* scores         = (float*)wsb;                                   // 1 MB
  unsigned short* Wfrag = (unsigned short*)(wsb + (size_t)B * S * 4);    // 128 KB
  float* dec            = (float*)(wsb + (size_t)B * S * 4 + (size_t)D * H * 2);  // 32 KB

  prep_kernel<<<96, 1024, 0, stream>>>(h0, c0, start_token, W_k, W_r, b_lstm,
                                       W_e, W_d, b_d, Wfrag, dec);
  attn_kernel<<<B * (S / 64), 256, 0, stream>>>(enc, Wfrag, dec, b_e, v_w, scores);
  softmax_kernel<<<B, 1024, 0, stream>>>(scores, out);
}

// Round 3
// 433.820 us; speedup vs baseline: 1.1535x; 1.1535x over previous
//
#include <hip/hip_runtime.h>
#include <hip/hip_bf16.h>
#include <stdint.h>

#define B 32
#define S 8192
#define D 256
#define H 256

typedef __attribute__((ext_vector_type(8))) short bf16x8;
typedef __attribute__((ext_vector_type(4))) float f32x4;

#define GLOBAL_AS __attribute__((address_space(1)))
#define LDS_AS __attribute__((address_space(3)))

__device__ inline unsigned short f2bf(float f) {
  unsigned u = __float_as_uint(f);
  unsigned r = (u + 0x7FFFu + ((u >> 16) & 1u)) >> 16;
  return (unsigned short)r;
}

__device__ inline unsigned pk2bf(float a, float b) {
  __hip_bfloat162 h = __float22bfloat162_rn(make_float2(a, b));
  unsigned u;
  __builtin_memcpy(&u, &h, 4);
  return u;
}

__device__ inline bf16x8 pack8(float4 a, float4 b) {
  union { unsigned u[4]; bf16x8 v; } c;
  c.u[0] = pk2bf(a.x, a.y);
  c.u[1] = pk2bf(a.z, a.w);
  c.u[2] = pk2bf(b.x, b.y);
  c.u[3] = pk2bf(b.z, b.w);
  return c.v;
}

__device__ inline float fast_tanh(float x) {
  float e = __expf(2.0f * x);
  return 1.0f - 2.0f * __builtin_amdgcn_rcpf(1.0f + e);
}

// ---------------------------------------------------------------------------
// Prep: blocks 0..63 swizzle W_e -> MFMA-B fragment-sequential bf16;
//       blocks 64..95: LSTM cell + dec_proj + b_d + b_e -> combined bias.
// ---------------------------------------------------------------------------
__global__ __launch_bounds__(1024) void prep_kernel(
    const float* __restrict__ h0, const float* __restrict__ c0,
    const float* __restrict__ start_token, const float* __restrict__ W_k,
    const float* __restrict__ W_r, const float* __restrict__ b_lstm,
    const float* __restrict__ W_e, const float* __restrict__ W_d,
    const float* __restrict__ b_d, const float* __restrict__ b_e,
    unsigned short* __restrict__ Wfrag, float* __restrict__ decb) {
  int blk = blockIdx.x;
  int tid = threadIdx.x;

  __shared__ float xs[D], hs[H], zs[4 * H], hv[H], dpp[4][H];

  if (blk < 64) {
    // idx = (((nt*8 + kt)*64 + lane)*8 + j); lane holds B[k][n],
    // n = nt*16 + (lane&15), k = kt*32 + (lane>>4)*8 + j
    int gid = blk * 1024 + tid;
    int j = gid & 7;
    int lane = (gid >> 3) & 63;
    int kt = (gid >> 9) & 7;
    int nt = gid >> 12;
    int n = nt * 16 + (lane & 15);
    int k = kt * 32 + (lane >> 4) * 8 + j;
    Wfrag[gid] = f2bf(W_e[k * H + n]);
  } else {
    int b = blk - 64;
    if (tid < D) xs[tid] = start_token[b * D + tid];
    else if (tid < 2 * D) hs[tid - D] = h0[b * H + (tid - D)];
    __syncthreads();
    {
      int jj = tid;
      float a0 = 0.f, a1 = 0.f, a2 = 0.f, a3 = 0.f;
      #pragma unroll 8
      for (int d = 0; d < D; d += 4) {
        a0 += xs[d + 0] * W_k[(d + 0) * 1024 + jj];
        a1 += xs[d + 1] * W_k[(d + 1) * 1024 + jj];
        a2 += xs[d + 2] * W_k[(d + 2) * 1024 + jj];
        a3 += xs[d + 3] * W_k[(d + 3) * 1024 + jj];
      }
      #pragma unroll 8
      for (int h = 0; h < H; h += 4) {
        a0 += hs[h + 0] * W_r[(h + 0) * 1024 + jj];
        a1 += hs[h + 1] * W_r[(h + 1) * 1024 + jj];
        a2 += hs[h + 2] * W_r[(h + 2) * 1024 + jj];
        a3 += hs[h + 3] * W_r[(h + 3) * 1024 + jj];
      }
      zs[jj] = b_lstm[jj] + ((a0 + a1) + (a2 + a3));
    }
    __syncthreads();
    if (tid < H) {
      float zi = zs[tid], zf = zs[H + tid], zg = zs[2 * H + tid], zo = zs[3 * H + tid];
      float si = 1.0f / (1.0f + expf(-zi));
      float sf = 1.0f / (1.0f + expf(-zf));
      float so = 1.0f / (1.0f + expf(-zo));
      float c = sf * c0[b * H + tid] + si * tanhf(zg);
      hv[tid] = so * tanhf(c);
    }
    __syncthreads();
    {
      int hcol = tid & (H - 1);
      int q = tid >> 8;
      float a = 0.f;
      #pragma unroll 8
      for (int k = q * 64; k < q * 64 + 64; ++k) a += hv[k] * W_d[k * H + hcol];
      dpp[q][hcol] = a;
    }
    __syncthreads();
    if (tid < H)
      decb[b * H + tid] = dpp[0][tid] + dpp[1][tid] + dpp[2][tid] + dpp[3][tid]
                        + b_d[tid] + b_e[tid];
  }
}

// ---------------------------------------------------------------------------
// Main: 512 persistent blocks x 16 tiles of 32 rows. Double-buffered LDS
// (2 x 32KB fp32, XOR-swizzled for bank-balanced ds_read_b128), staged via
// async global_load_lds width=16 (zero VGPR cost, 32KB in flight/block).
// B fragments live in registers for the whole kernel. Prefetch is issued
// AFTER the barrier so its vmcnt drain lands at the NEXT barrier, a full
// compute phase later. Per-wave partials go to scores4[row][wave].
// ---------------------------------------------------------------------------
__global__ __launch_bounds__(256, 2) void attn_kernel(
    const float* __restrict__ enc, const unsigned short* __restrict__ Wfrag,
    const float* __restrict__ decb, const float* __restrict__ v_w,
    float* __restrict__ scores4) {
  __shared__ float Abuf[2][32 * 256];  // exactly 64 KB

  const int tid = threadIdx.x;
  const int wave = tid >> 6, lane = tid & 63;
  const int ml = lane & 15, kg = lane >> 4;
  const int bid = blockIdx.x;            // 512 blocks
  const int batch = bid >> 4;            // 16 blocks per batch
  const long row_blk = (long)bid * 512;  // 16 tiles * 32 rows

  // B fragments: persistent in registers (4 nt x 8 kt x 4 VGPR = 128 VGPRs)
  bf16x8 wfr[4][8];
  #pragma unroll
  for (int q = 0; q < 4; ++q)
    #pragma unroll
    for (int kt = 0; kt < 8; ++kt)
      wfr[q][kt] = *(const bf16x8*)(Wfrag + ((size_t)(((wave * 4 + q) * 8 + kt) * 64 + lane) << 3));

  // Epilogue constants (wave's 64-col slice: n = wave*64 + q*16 + ml)
  float bs[4], vw[4];
  #pragma unroll
  for (int q = 0; q < 4; ++q) {
    int n = wave * 64 + q * 16 + ml;
    bs[q] = decb[batch * 256 + n];
    vw[q] = v_w[n];
  }

  // Async stage of tile t into Abuf[sel]: slot(row,c) = row*64 + (c^(row&7)),
  // LDS dest = uniform base + lane*16 (HW rule); chunk c = lane^(row&7) makes
  // each wave cover one contiguous 1KB row -> fully coalesced.
  auto stage = [&](int t, int sel) {
    const float* gtile = enc + (row_blk + (long)t * 32) * D;
    #pragma unroll
    for (int is = 0; is < 8; ++is) {
      int row = is * 4 + wave;
      int c = lane ^ (row & 7);
      const float* gp = gtile + row * D + c * 4;
      float* lp = &Abuf[sel][(is * 256 + wave * 64) * 4];
      __builtin_amdgcn_global_load_lds((const GLOBAL_AS void*)gp,
                                       (LDS_AS void*)lp, 16, 0, 0);
    }
  };

  stage(0, 0);

  #pragma unroll 2
  for (int t = 0; t < 16; ++t) {
    __syncthreads();  // tile t resident; prefetch t+1 drains at NEXT barrier
    if (t + 1 < 16) stage(t + 1, (t + 1) & 1);

    const float* Ab = Abuf[t & 1];
    f32x4 acc[2][4];
    #pragma unroll
    for (int i = 0; i < 2; ++i)
      #pragma unroll
      for (int q = 0; q < 4; ++q) acc[i][q] = (f32x4){0.f, 0.f, 0.f, 0.f};

    #pragma unroll
    for (int kt = 0; kt < 8; ++kt) {
      #pragma unroll
      for (int i = 0; i < 2; ++i) {
        int row = i * 16 + ml;
        int x = ml & 7;
        int c0 = kt * 8 + kg * 2;
        float4 v0 = *(const float4*)&Ab[(row * 64 + (c0 ^ x)) * 4];
        float4 v1 = *(const float4*)&Ab[(row * 64 + ((c0 + 1) ^ x)) * 4];
        bf16x8 af = pack8(v0, v1);
        #pragma unroll
        for (int q = 0; q < 4; ++q)
          acc[i][q] = __builtin_amdgcn_mfma_f32_16x16x32_bf16(af, wfr[q][kt], acc[i][q], 0, 0, 0);
      }
    }

    // Epilogue: t = tanh(acc + bias[n]); partial over this wave's 64 cols
    float part[8];
    #pragma unroll
    for (int v = 0; v < 8; ++v) part[v] = 0.f;
    #pragma unroll
    for (int q = 0; q < 4; ++q)
      #pragma unroll
      for (int i = 0; i < 2; ++i)
        #pragma unroll
        for (int r = 0; r < 4; ++r)
          part[i * 4 + r] += fast_tanh(acc[i][q][r] + bs[q]) * vw[q];
    // reduce over the 16 column-lanes (lane bits 0..3)
    #pragma unroll
    for (int m = 1; m < 16; m <<= 1)
      #pragma unroll
      for (int v = 0; v < 8; ++v) part[v] += __shfl_xor(part[v], m, 64);
    if (ml == 0) {
      long r0 = row_blk + (long)t * 32 + kg * 4;  // C row = kg*4 + r (+ i*16)
      #pragma unroll
      for (int i = 0; i < 2; ++i)
        #pragma unroll
        for (int r = 0; r < 4; ++r)
          scores4[(r0 + i * 16 + r) * 4 + wave] = part[i * 4 + r];
    }
  }
}

// ---------------------------------------------------------------------------
// Softmax over each row of (B, S); input scores4[row][4] wave-partials.
// ---------------------------------------------------------------------------
__global__ __launch_bounds__(1024) void softmax_kernel(
    const float* __restrict__ scores4, float* __restrict__ out) {
  int b = blockIdx.x;
  int tid = threadIdx.x;
  __shared__ float red[16];
  const float* src = scores4 + (long)b * S * 4;
  float v[8];
  float lmax = -1e30f;
  #pragma unroll
  for (int j = 0; j < 8; ++j) {
    float4 t4 = *(const float4*)(src + (size_t)(tid + j * 1024) * 4);
    v[j] = (t4.x + t4.y) + (t4.z + t4.w);
    lmax = fmaxf(lmax, v[j]);
  }
  #pragma unroll
  for (int m = 1; m < 64; m <<= 1) lmax = fmaxf(lmax, __shfl_xor(lmax, m, 64));
  if ((tid & 63) == 0) red[tid >> 6] = lmax;
  __syncthreads();
  float M = red[0];
  #pragma unroll
  for (int i = 1; i < 16; ++i) M = fmaxf(M, red[i]);
  __syncthreads();
  float ls = 0.f;
  #pragma unroll
  for (int j = 0; j < 8; ++j) {
    v[j] = __expf(v[j] - M);
    ls += v[j];
  }
  #pragma unroll
  for (int m = 1; m < 64; m <<= 1) ls += __shfl_xor(ls, m, 64);
  if ((tid & 63) == 0) red[tid >> 6] = ls;
  __syncthreads();
  float total = 0.f;
  #pragma unroll
  for (int i = 0; i < 16; ++i) total += red[i];
  float inv = __builtin_amdgcn_rcpf(total);
  #pragma unroll
  for (int j = 0; j < 8; ++j) out[(long)b * S + tid + j * 1024] = v[j] * inv;
}

extern "C" void kernel_launch(void* const* d_in, const int* in_sizes, int n_in,
                              void* d_out, int out_size, void* d_ws, size_t ws_size,
                              hipStream_t stream) {
  const float* enc         = (const float*)d_in[0];
  const float* h0          = (const float*)d_in[1];
  const float* c0          = (const float*)d_in[2];
  const float* start_token = (const float*)d_in[3];
  const float* W_k         = (const float*)d_in[4];
  const float* W_r         = (const float*)d_in[5];
  const float* b_lstm      = (const float*)d_in[6];
  const float* W_e         = (const float*)d_in[7];
  const float* b_e         = (const float*)d_in[8];
  const float* W_d         = (const float*)d_in[9];
  const float* b_d         = (const float*)d_in[10];
  const float* v_w         = (const float*)d_in[11];
  // d_in[12] = v_b: softmax(s + c) == softmax(s), cancels exactly.
  float* out = (float*)d_out;

  char* wsb = (char*)d_ws;
  float* scores4        = (float*)wsb;                                    // B*S*4*4 = 4 MB
  unsigned short* Wfrag = (unsigned short*)(wsb + (size_t)B * S * 16);    // 128 KB
  float* decb           = (float*)(wsb + (size_t)B * S * 16 + (size_t)D * H * 2);  // 32 KB

  prep_kernel<<<96, 1024, 0, stream>>>(h0, c0, start_token, W_k, W_r, b_lstm,
                                       W_e, W_d, b_d, b_e, Wfrag, decb);
  attn_kernel<<<512, 256, 0, stream>>>(enc, Wfrag, decb, v_w, scores4);
  softmax_kernel<<<B, 1024, 0, stream>>>(scores4, out);
}